// Round 6
// baseline (199.088 us; speedup 1.0000x reference)
//
#include <hip/hip_runtime.h>

// ---------------------------------------------------------------------------
// GMMConv forward (ws budget: 25.6 MB — proven since R2):
//  0) convert_inputs: Wp[j'][k]=bf16(W_fc[((j'&3)<<6)|(j'>>2)][k]) into a
//     128 KB overlay at the start of d_out (edge rewrites all of d_out
//     afterwards); Af = bf16(feat) into ws. One streaming pass (~77 MB).
//  1) gemm_inplace: nf = Af @ Wp.T IN PLACE over the same ws buffer (each
//     block reads only its own 64 rows during K, overwrites them in the
//     epilogue). m97 recipe: 16B global_load_lds, unpadded 64B LDS rows,
//     16x16x32 bf16 MFMA. UNCHANGED from R5 for clean attribution.
//  2) edge_aggregate: one wave per dst node (CSR rowptr sorts edges by dst,
//     no atomics). NEW: depth-4 software-pipelined gather (R3 showed
//     unroll-16 thrashes; rolled loop had only 1 gather in flight).
//     All 16 chunk slots always staged (g=0/col=0 for dead slots) so the
//     4-wide inner loop is branch-free.
// ---------------------------------------------------------------------------

typedef __attribute__((ext_vector_type(8))) short bf16x8;
typedef __attribute__((ext_vector_type(4))) float f32x4;

__device__ inline unsigned short f32_to_bf16(float f) {
    union { float f; unsigned int u; } c; c.f = f;
    unsigned int u = c.u;
    u += 0x7fffu + ((u >> 16) & 1u);   // round-to-nearest-even
    return (unsigned short)(u >> 16);
}
__device__ inline float bf16_to_f32(unsigned short h) {
    union { unsigned int u; float f; } c; c.u = ((unsigned int)h) << 16;
    return c.f;
}
__device__ inline ushort4 cvt4(float4 v) {
    ushort4 h;
    h.x = f32_to_bf16(v.x); h.y = f32_to_bf16(v.y);
    h.z = f32_to_bf16(v.z); h.w = f32_to_bf16(v.w);
    return h;
}

// W permute+convert (first 16384 float4) + feat convert (grid-stride).
__global__ __launch_bounds__(256) void convert_inputs(
    const float* __restrict__ W, const float* __restrict__ feat,
    unsigned short* __restrict__ Wp, unsigned short* __restrict__ Af,
    int nFeat4)
{
    const int gid = blockIdx.x * 256 + threadIdx.x;
    if (gid < 16384) {
        const int jp = gid >> 6, k4 = gid & 63;
        const int wrow = ((jp & 3) << 6) | (jp >> 2);
        reinterpret_cast<ushort4*>(Wp)[jp * 64 + k4] =
            cvt4(reinterpret_cast<const float4*>(W)[wrow * 64 + k4]);
    }
    for (int i = gid; i < nFeat4; i += gridDim.x * 256)
        reinterpret_cast<ushort4*>(Af)[i] =
            cvt4(reinterpret_cast<const float4*>(feat)[i]);
}

// In-place: AC holds Af bf16 [M][256] on entry, nf bf16 [M][256] on exit.
__global__ __launch_bounds__(256) void gemm_inplace(
    unsigned short* AC,                     // aliases: A in, C out (same rows)
    const unsigned short* __restrict__ Wp,  // bf16 [256][256] permuted rows
    int M)
{
    __shared__ unsigned short As[64 * 32];   //  4 KB, 64 B/row (unpadded: DMA)
    __shared__ unsigned short Bs[256 * 32];  // 16 KB
    const int t    = threadIdx.x;
    const int lane = t & 63;
    const int wave = t >> 6;
    const int bm   = blockIdx.x * 64;
    const int l16  = lane & 15;
    const int quad = lane >> 4;
    const int wn   = wave * 64;

    const int kc   = (lane & 3) * 8;
    const int arow = min(bm + wave * 16 + (lane >> 2), M - 1);
    const size_t asrc = (size_t)arow * 256 + kc;
    size_t bsrc[4];
#pragma unroll
    for (int j = 0; j < 4; ++j)
        bsrc[j] = (size_t)(wave * 64 + j * 16 + (lane >> 2)) * 256 + kc;

    f32x4 acc[4][4];
#pragma unroll
    for (int mi = 0; mi < 4; ++mi)
#pragma unroll
        for (int ni = 0; ni < 4; ++ni)
            acc[mi][ni] = (f32x4){0.f, 0.f, 0.f, 0.f};

    typedef __attribute__((address_space(3))) void lds_t;
    typedef const __attribute__((address_space(1))) void gm_t;

    for (int k0 = 0; k0 < 256; k0 += 32) {
        __builtin_amdgcn_global_load_lds((gm_t*)(AC + asrc + k0),
            (lds_t*)(As + wave * 512), 16, 0, 0);
#pragma unroll
        for (int j = 0; j < 4; ++j)
            __builtin_amdgcn_global_load_lds((gm_t*)(Wp + bsrc[j] + k0),
                (lds_t*)(Bs + (wave * 4 + j) * 512), 16, 0, 0);
        __syncthreads();

        bf16x8 af[4], bfr[4];
#pragma unroll
        for (int mi = 0; mi < 4; ++mi)
            af[mi] = *reinterpret_cast<const bf16x8*>(
                &As[(mi * 16 + l16) * 32 + quad * 8]);
#pragma unroll
        for (int ni = 0; ni < 4; ++ni)
            bfr[ni] = *reinterpret_cast<const bf16x8*>(
                &Bs[(wn + ni * 16 + l16) * 32 + quad * 8]);
#pragma unroll
        for (int mi = 0; mi < 4; ++mi)
#pragma unroll
            for (int ni = 0; ni < 4; ++ni)
                acc[mi][ni] = __builtin_amdgcn_mfma_f32_16x16x32_bf16(
                    af[mi], bfr[ni], acc[mi][ni], 0, 0, 0);
        __syncthreads();
    }

    // C/D layout: col = lane&15, row = quad*4 + reg   [m89-verified]
#pragma unroll
    for (int mi = 0; mi < 4; ++mi) {
#pragma unroll
        for (int r = 0; r < 4; ++r) {
            const int row = bm + mi * 16 + quad * 4 + r;
            if (row < M) {
#pragma unroll
                for (int ni = 0; ni < 4; ++ni) {
                    const int col = wn + ni * 16 + l16;
                    AC[(size_t)row * 256 + col] = f32_to_bf16(acc[mi][ni][r]);
                }
            }
        }
    }
}

// One wave per destination node; lane = feature f (F=64). 2 waves/block.
__global__ __launch_bounds__(128) void edge_aggregate(
    const int* __restrict__ rowptr,
    const int* __restrict__ colind,
    const float* __restrict__ pseudo,       // [E][2]
    const unsigned short* __restrict__ nf,  // bf16 [N][256] permuted [f*4+k]
    const float* __restrict__ mu,
    const float* __restrict__ inv_sigma,
    const float* __restrict__ bias,
    float* __restrict__ out,                // [N][64]
    int N)
{
    __shared__ float gbuf[2][64];
    __shared__ int   cbuf[2][16];
    const int wave = threadIdx.x >> 6;
    const int lane = threadIdx.x & 63;
    const int node = blockIdx.x * 2 + wave;
    if (node >= N) return;          // wave-uniform exit; no block barriers below

    const int kk = lane >> 4;
    const int ii = lane & 15;
    const float mx = mu[2 * kk], my = mu[2 * kk + 1];
    const float sa = inv_sigma[2 * kk], sb = inv_sigma[2 * kk + 1];
    const float sx = sa * sa, sy = sb * sb;

    const int e0 = rowptr[node];
    const int e1 = rowptr[node + 1];
    float* gw = gbuf[wave];
    int*   cw = cbuf[wave];

    float acc = 0.f;
    for (int ec = e0; ec < e1; ec += 16) {
        const int cnt = min(16, e1 - ec);
        // stage all 16 slots: dead slots get g=0, col=0 (row-0 gather * 0)
        {
            const bool v = ii < cnt;
            const int e = v ? (ec + ii) : e0;
            const float2 p = *reinterpret_cast<const float2*>(pseudo + 2 * (size_t)e);
            const float dx = p.x - mx, dy = p.y - my;
            const float g = v ? __expf(-0.5f * (dx * dx * sx + dy * dy * sy)) : 0.f;
            gw[ii * 4 + kk] = g;
            if (kk == 0) cw[ii] = v ? colind[e] : 0;
        }
        __builtin_amdgcn_wave_barrier();
        __threadfence_block();      // drain LDS writes before broadcast reads
        const int cnt4 = (cnt + 3) & ~3;
        for (int i2 = 0; i2 < cnt4; i2 += 4) {
            // 4 gathers issued back-to-back -> 4 outstanding per wave
            const int c0 = cw[i2 + 0], c1 = cw[i2 + 1];
            const int c2 = cw[i2 + 2], c3 = cw[i2 + 3];
            const ushort4 h0 = *reinterpret_cast<const ushort4*>(nf + ((size_t)c0 << 8) + (lane << 2));
            const ushort4 h1 = *reinterpret_cast<const ushort4*>(nf + ((size_t)c1 << 8) + (lane << 2));
            const ushort4 h2 = *reinterpret_cast<const ushort4*>(nf + ((size_t)c2 << 8) + (lane << 2));
            const ushort4 h3 = *reinterpret_cast<const ushort4*>(nf + ((size_t)c3 << 8) + (lane << 2));
            const float4 g0 = *reinterpret_cast<const float4*>(&gw[(i2 + 0) * 4]);
            const float4 g1 = *reinterpret_cast<const float4*>(&gw[(i2 + 1) * 4]);
            const float4 g2 = *reinterpret_cast<const float4*>(&gw[(i2 + 2) * 4]);
            const float4 g3 = *reinterpret_cast<const float4*>(&gw[(i2 + 3) * 4]);
            acc += g0.x * bf16_to_f32(h0.x) + g0.y * bf16_to_f32(h0.y)
                 + g0.z * bf16_to_f32(h0.z) + g0.w * bf16_to_f32(h0.w);
            acc += g1.x * bf16_to_f32(h1.x) + g1.y * bf16_to_f32(h1.y)
                 + g1.z * bf16_to_f32(h1.z) + g1.w * bf16_to_f32(h1.w);
            acc += g2.x * bf16_to_f32(h2.x) + g2.y * bf16_to_f32(h2.y)
                 + g2.z * bf16_to_f32(h2.z) + g2.w * bf16_to_f32(h2.w);
            acc += g3.x * bf16_to_f32(h3.x) + g3.y * bf16_to_f32(h3.y)
                 + g3.z * bf16_to_f32(h3.z) + g3.w * bf16_to_f32(h3.w);
        }
        __builtin_amdgcn_wave_barrier();
        __threadfence_block();      // reads done before next chunk's writes
    }
    out[((size_t)node << 6) + lane] = acc + bias[lane];
}

extern "C" void kernel_launch(void* const* d_in, const int* in_sizes, int n_in,
                              void* d_out, int out_size, void* d_ws, size_t ws_size,
                              hipStream_t stream)
{
    const int*   rowptr    = (const int*)d_in[0];
    const int*   colind    = (const int*)d_in[1];
    // d_in[2] colptr, d_in[3] rowind, d_in[4] permute: inert in forward math
    const float* feat      = (const float*)d_in[5];
    const float* pseudo    = (const float*)d_in[6];
    const float* W_fc      = (const float*)d_in[7];
    const float* mu        = (const float*)d_in[8];
    const float* inv_sigma = (const float*)d_in[9];
    const float* bias      = (const float*)d_in[10];
    float* out = (float*)d_out;

    const int N = in_sizes[0] - 1;                 // 50000
    unsigned short* AC = (unsigned short*)d_ws;    // Af in / nf out, 25.6 MB
    unsigned short* Wp = (unsigned short*)d_out;   // 128 KB overlay; edge
                                                   // rewrites d_out afterwards

    hipLaunchKernelGGL(convert_inputs, dim3(1024), dim3(256), 0, stream,
                       W_fc, feat, Wp, AC, N * 64);

    hipLaunchKernelGGL(gemm_inplace, dim3((N + 63) / 64), dim3(256), 0, stream,
                       AC, Wp, N);

    hipLaunchKernelGGL(edge_aggregate, dim3((N + 1) / 2), dim3(128), 0, stream,
                       rowptr, colind, pseudo, AC, mu, inv_sigma, bias, out, N);
}

// Round 7
// 192.045 us; speedup vs baseline: 1.0367x; 1.0367x over previous
//
#include <hip/hip_runtime.h>

// ---------------------------------------------------------------------------
// GMMConv forward (edge kernel FROZEN from R6 for attribution):
//  0) convert_W: Wp[j'][k]=bf16(W_fc[((j'&3)<<6)|(j'>>2)][k]) into a 128 KB
//     overlay at the start of d_out (edge rewrites all of d_out afterwards).
//     Tiny: 0.26 MB.
//  1) gemm_fused: nf = bf16(feat) @ Wp.T with NO separate feat-convert pass:
//     each block VALU-converts its own 64x256 fp32 A rows into LDS ONCE
//     (33 KB), then runs 8 k-iters with 16 KB B-tile DMA (global_load_lds
//     width=16) from the L2-resident Wp + 16x16x32 bf16 MFMA. MFMA is issued
//     after the next B-DMA so the ~200cyc L2 latency is overlapped.
//     GEMM-path HBM traffic: 51.2 (feat) + 25.6 (nf) + 0.5 MB = 77 MB.
//  2) edge_aggregate: UNCHANGED R6 body. One wave per dst node (CSR rowptr
//     sorts edges by dst -> no atomics); cooperative gaussians in LDS;
//     depth-4 pipelined gather (measured at the ~6 TB/s fabric wall).
// ---------------------------------------------------------------------------

typedef __attribute__((ext_vector_type(8))) short bf16x8;
typedef __attribute__((ext_vector_type(4))) float f32x4;

__device__ inline unsigned short f32_to_bf16(float f) {
    union { float f; unsigned int u; } c; c.f = f;
    unsigned int u = c.u;
    u += 0x7fffu + ((u >> 16) & 1u);   // round-to-nearest-even
    return (unsigned short)(u >> 16);
}
__device__ inline float bf16_to_f32(unsigned short h) {
    union { unsigned int u; float f; } c; c.u = ((unsigned int)h) << 16;
    return c.f;
}
__device__ inline ushort4 cvt4(float4 v) {
    ushort4 h;
    h.x = f32_to_bf16(v.x); h.y = f32_to_bf16(v.y);
    h.z = f32_to_bf16(v.z); h.w = f32_to_bf16(v.w);
    return h;
}

// W_fc fp32 [256][256] -> Wp bf16 [256][256] with permuted rows.
__global__ __launch_bounds__(256) void convert_W(
    const float* __restrict__ W, unsigned short* __restrict__ Wp)
{
    const int gid = blockIdx.x * 256 + threadIdx.x;   // 64 blocks -> 16384
    const int jp = gid >> 6, k4 = gid & 63;
    const int wrow = ((jp & 3) << 6) | (jp >> 2);
    reinterpret_cast<ushort4*>(Wp)[jp * 64 + k4] =
        cvt4(reinterpret_cast<const float4*>(W)[wrow * 64 + k4]);
}

#define ASTRIDE 264   // shorts per A-row in LDS (+8 pad kills b128 conflicts)

// nf[m][jp] = sum_k bf16(feat[m][k]) * Wp[jp][k]
// Block: 64 rows x 256 cols, 4 waves (wave w -> cols w*64..w*64+63).
__global__ __launch_bounds__(256) void gemm_fused(
    const float* __restrict__ feat,         // fp32 [M][256]
    const unsigned short* __restrict__ Wp,  // bf16 [256][256] permuted rows
    unsigned short* __restrict__ nf,        // bf16 [M][256]
    int M)
{
    __shared__ unsigned short As[64 * ASTRIDE];  // 33 KB: full 64x256 A tile
    __shared__ unsigned short Bs[256 * 32];      // 16 KB: one 256x32 B tile
    const int t    = threadIdx.x;
    const int lane = t & 63;
    const int wave = t >> 6;
    const int bm   = blockIdx.x * 64;
    const int l16  = lane & 15;
    const int quad = lane >> 4;
    const int wn   = wave * 64;

    // B-tile DMA mapping (1 KB chunk: lane l -> row chunk*16+(l>>2), k (l&3)*8)
    size_t bsrc[4];
#pragma unroll
    for (int j = 0; j < 4; ++j)
        bsrc[j] = (size_t)(wave * 64 + j * 16 + (lane >> 2)) * 256 + (lane & 3) * 8;

    typedef __attribute__((address_space(3))) void lds_t;
    typedef const __attribute__((address_space(1))) void gm_t;

    // kick off B DMA for k0=0, then stage A (fp32->bf16) while it flies
#pragma unroll
    for (int j = 0; j < 4; ++j)
        __builtin_amdgcn_global_load_lds((gm_t*)(Wp + bsrc[j]),
            (lds_t*)(Bs + (wave * 4 + j) * 512), 16, 0, 0);

    // stage A once: iter it, thread t -> 8 consecutive floats
#pragma unroll
    for (int it = 0; it < 8; ++it) {
        const int flat = it * 2048 + t * 8;
        const int row  = flat >> 8;              // 0..63
        const int koff = flat & 255;
        const float* src = feat + (size_t)min(bm + row, M - 1) * 256 + koff;
        const float4 a0 = *reinterpret_cast<const float4*>(src);
        const float4 a1 = *reinterpret_cast<const float4*>(src + 4);
        *reinterpret_cast<ushort4*>(&As[row * ASTRIDE + koff])     = cvt4(a0);
        *reinterpret_cast<ushort4*>(&As[row * ASTRIDE + koff + 4]) = cvt4(a1);
    }

    f32x4 acc[4][4];
#pragma unroll
    for (int mi = 0; mi < 4; ++mi)
#pragma unroll
        for (int ni = 0; ni < 4; ++ni)
            acc[mi][ni] = (f32x4){0.f, 0.f, 0.f, 0.f};

    for (int ki = 0; ki < 8; ++ki) {
        __syncthreads();                         // Bs(ki) + As ready

        bf16x8 af[4], bfr[4];
#pragma unroll
        for (int mi = 0; mi < 4; ++mi)
            af[mi] = *reinterpret_cast<const bf16x8*>(
                &As[(mi * 16 + l16) * ASTRIDE + ki * 32 + quad * 8]);
#pragma unroll
        for (int ni = 0; ni < 4; ++ni)
            bfr[ni] = *reinterpret_cast<const bf16x8*>(
                &Bs[(wn + ni * 16 + l16) * 32 + quad * 8]);

        __syncthreads();                         // all waves done reading Bs
        if (ki < 7) {
            const int k0 = (ki + 1) * 32;
#pragma unroll
            for (int j = 0; j < 4; ++j)
                __builtin_amdgcn_global_load_lds((gm_t*)(Wp + bsrc[j] + k0),
                    (lds_t*)(Bs + (wave * 4 + j) * 512), 16, 0, 0);
        }
        // MFMA after DMA issue -> DMA latency overlapped by matrix pipe
#pragma unroll
        for (int mi = 0; mi < 4; ++mi)
#pragma unroll
            for (int ni = 0; ni < 4; ++ni)
                acc[mi][ni] = __builtin_amdgcn_mfma_f32_16x16x32_bf16(
                    af[mi], bfr[ni], acc[mi][ni], 0, 0, 0);
    }

    // C/D layout: col = lane&15, row = quad*4 + reg   [m89-verified]
#pragma unroll
    for (int mi = 0; mi < 4; ++mi) {
#pragma unroll
        for (int r = 0; r < 4; ++r) {
            const int row = bm + mi * 16 + quad * 4 + r;
            if (row < M) {
#pragma unroll
                for (int ni = 0; ni < 4; ++ni) {
                    const int col = wn + ni * 16 + l16;
                    nf[(size_t)row * 256 + col] = f32_to_bf16(acc[mi][ni][r]);
                }
            }
        }
    }
}

// One wave per destination node; lane = feature f (F=64). FROZEN R6 body.
__global__ __launch_bounds__(128) void edge_aggregate(
    const int* __restrict__ rowptr,
    const int* __restrict__ colind,
    const float* __restrict__ pseudo,       // [E][2]
    const unsigned short* __restrict__ nf,  // bf16 [N][256] permuted [f*4+k]
    const float* __restrict__ mu,
    const float* __restrict__ inv_sigma,
    const float* __restrict__ bias,
    float* __restrict__ out,                // [N][64]
    int N)
{
    __shared__ float gbuf[2][64];
    __shared__ int   cbuf[2][16];
    const int wave = threadIdx.x >> 6;
    const int lane = threadIdx.x & 63;
    const int node = blockIdx.x * 2 + wave;
    if (node >= N) return;          // wave-uniform exit; no block barriers below

    const int kk = lane >> 4;
    const int ii = lane & 15;
    const float mx = mu[2 * kk], my = mu[2 * kk + 1];
    const float sa = inv_sigma[2 * kk], sb = inv_sigma[2 * kk + 1];
    const float sx = sa * sa, sy = sb * sb;

    const int e0 = rowptr[node];
    const int e1 = rowptr[node + 1];
    float* gw = gbuf[wave];
    int*   cw = cbuf[wave];

    float acc = 0.f;
    for (int ec = e0; ec < e1; ec += 16) {
        const int cnt = min(16, e1 - ec);
        {
            const bool v = ii < cnt;
            const int e = v ? (ec + ii) : e0;
            const float2 p = *reinterpret_cast<const float2*>(pseudo + 2 * (size_t)e);
            const float dx = p.x - mx, dy = p.y - my;
            const float g = v ? __expf(-0.5f * (dx * dx * sx + dy * dy * sy)) : 0.f;
            gw[ii * 4 + kk] = g;
            if (kk == 0) cw[ii] = v ? colind[e] : 0;
        }
        __builtin_amdgcn_wave_barrier();
        __threadfence_block();
        const int cnt4 = (cnt + 3) & ~3;
        for (int i2 = 0; i2 < cnt4; i2 += 4) {
            const int c0 = cw[i2 + 0], c1 = cw[i2 + 1];
            const int c2 = cw[i2 + 2], c3 = cw[i2 + 3];
            const ushort4 h0 = *reinterpret_cast<const ushort4*>(nf + ((size_t)c0 << 8) + (lane << 2));
            const ushort4 h1 = *reinterpret_cast<const ushort4*>(nf + ((size_t)c1 << 8) + (lane << 2));
            const ushort4 h2 = *reinterpret_cast<const ushort4*>(nf + ((size_t)c2 << 8) + (lane << 2));
            const ushort4 h3 = *reinterpret_cast<const ushort4*>(nf + ((size_t)c3 << 8) + (lane << 2));
            const float4 g0 = *reinterpret_cast<const float4*>(&gw[(i2 + 0) * 4]);
            const float4 g1 = *reinterpret_cast<const float4*>(&gw[(i2 + 1) * 4]);
            const float4 g2 = *reinterpret_cast<const float4*>(&gw[(i2 + 2) * 4]);
            const float4 g3 = *reinterpret_cast<const float4*>(&gw[(i2 + 3) * 4]);
            acc += g0.x * bf16_to_f32(h0.x) + g0.y * bf16_to_f32(h0.y)
                 + g0.z * bf16_to_f32(h0.z) + g0.w * bf16_to_f32(h0.w);
            acc += g1.x * bf16_to_f32(h1.x) + g1.y * bf16_to_f32(h1.y)
                 + g1.z * bf16_to_f32(h1.z) + g1.w * bf16_to_f32(h1.w);
            acc += g2.x * bf16_to_f32(h2.x) + g2.y * bf16_to_f32(h2.y)
                 + g2.z * bf16_to_f32(h2.z) + g2.w * bf16_to_f32(h2.w);
            acc += g3.x * bf16_to_f32(h3.x) + g3.y * bf16_to_f32(h3.y)
                 + g3.z * bf16_to_f32(h3.z) + g3.w * bf16_to_f32(h3.w);
        }
        __builtin_amdgcn_wave_barrier();
        __threadfence_block();
    }
    out[((size_t)node << 6) + lane] = acc + bias[lane];
}

extern "C" void kernel_launch(void* const* d_in, const int* in_sizes, int n_in,
                              void* d_out, int out_size, void* d_ws, size_t ws_size,
                              hipStream_t stream)
{
    const int*   rowptr    = (const int*)d_in[0];
    const int*   colind    = (const int*)d_in[1];
    // d_in[2] colptr, d_in[3] rowind, d_in[4] permute: inert in forward math
    const float* feat      = (const float*)d_in[5];
    const float* pseudo    = (const float*)d_in[6];
    const float* W_fc      = (const float*)d_in[7];
    const float* mu        = (const float*)d_in[8];
    const float* inv_sigma = (const float*)d_in[9];
    const float* bias      = (const float*)d_in[10];
    float* out = (float*)d_out;

    const int N = in_sizes[0] - 1;                 // 50000
    unsigned short* nf = (unsigned short*)d_ws;    // bf16 [N][256] = 25.6 MB
    unsigned short* Wp = (unsigned short*)d_out;   // 128 KB overlay; edge
                                                   // rewrites d_out afterwards

    hipLaunchKernelGGL(convert_W, dim3(64), dim3(256), 0, stream, W_fc, Wp);

    hipLaunchKernelGGL(gemm_fused, dim3((N + 63) / 64), dim3(256), 0, stream,
                       feat, Wp, nf, N);

    hipLaunchKernelGGL(edge_aggregate, dim3((N + 1) / 2), dim3(128), 0, stream,
                       rowptr, colind, pseudo, nf, mu, inv_sigma, bias, out, N);
}

// Round 8
// 189.620 us; speedup vs baseline: 1.0499x; 1.0128x over previous
//
#include <hip/hip_runtime.h>

// ---------------------------------------------------------------------------
// GMMConv forward — fp16 edition:
//  0) convert_W: Wp[j'][k]=f16(W_fc[((j'&3)<<6)|(j'>>2)][k]) into a 128 KB
//     overlay at the start of d_out (edge rewrites all of d_out afterwards).
//  1) gemm_fused: nf = f16(feat) @ Wp.T. Per block: VALU-convert own 64x256
//     fp32 A rows into LDS once, then 8 k-iters of 16 KB B-tile DMA
//     (global_load_lds width=16, L2-resident Wp) + 16x16x32 f16 MFMA.
//     nf layout [m][f*4+k] so the edge gather is one 8B load per lane.
//  2) edge_aggregate: one wave per dst node (CSR rowptr sorts edges by dst,
//     no atomics). Cooperative gaussians in LDS (f16). Inner loop: 2 x
//     v_dot2_f32_f16 per edge + 4 independent accumulators (breaks the
//     serial FMA chain that paced R5-R7's loop).
//  fp16 vs bf16: same bytes, 8x the mantissa -> absmax improves; |nf|<~20
//  and g in [0,1] are far inside fp16 range.
// ---------------------------------------------------------------------------

typedef _Float16 f16;
typedef __attribute__((ext_vector_type(2))) _Float16 f16x2;
typedef __attribute__((ext_vector_type(4))) _Float16 f16x4;
typedef __attribute__((ext_vector_type(8))) _Float16 f16x8;
typedef __attribute__((ext_vector_type(4))) float f32x4;

__device__ inline f16x4 cvt4h(float4 v) {
    f16x4 h;
    h.x = (f16)v.x; h.y = (f16)v.y; h.z = (f16)v.z; h.w = (f16)v.w;
    return h;
}

// W_fc fp32 [256][256] -> Wp f16 [256][256] with permuted rows.
__global__ __launch_bounds__(256) void convert_W(
    const float* __restrict__ W, f16* __restrict__ Wp)
{
    const int gid = blockIdx.x * 256 + threadIdx.x;   // 64 blocks -> 16384
    const int jp = gid >> 6, k4 = gid & 63;
    const int wrow = ((jp & 3) << 6) | (jp >> 2);
    reinterpret_cast<f16x4*>(Wp)[jp * 64 + k4] =
        cvt4h(reinterpret_cast<const float4*>(W)[wrow * 64 + k4]);
}

#define ASTRIDE 264   // f16 per A-row in LDS (+8 pad kills b128 conflicts)

// nf[m][jp] = sum_k f16(feat[m][k]) * Wp[jp][k]
// Block: 64 rows x 256 cols, 4 waves (wave w -> cols w*64..w*64+63).
__global__ __launch_bounds__(256) void gemm_fused(
    const float* __restrict__ feat,   // fp32 [M][256]
    const f16* __restrict__ Wp,       // f16 [256][256] permuted rows
    f16* __restrict__ nf,             // f16 [M][256]
    int M)
{
    __shared__ f16 As[64 * ASTRIDE];  // 33 KB: full 64x256 A tile
    __shared__ f16 Bs[256 * 32];      // 16 KB: one 256x32 B tile
    const int t    = threadIdx.x;
    const int lane = t & 63;
    const int wave = t >> 6;
    const int bm   = blockIdx.x * 64;
    const int l16  = lane & 15;
    const int quad = lane >> 4;
    const int wn   = wave * 64;

    size_t bsrc[4];
#pragma unroll
    for (int j = 0; j < 4; ++j)
        bsrc[j] = (size_t)(wave * 64 + j * 16 + (lane >> 2)) * 256 + (lane & 3) * 8;

    typedef __attribute__((address_space(3))) void lds_t;
    typedef const __attribute__((address_space(1))) void gm_t;

    // kick off B DMA for k0=0, then stage A (fp32->f16) while it flies
#pragma unroll
    for (int j = 0; j < 4; ++j)
        __builtin_amdgcn_global_load_lds((gm_t*)(Wp + bsrc[j]),
            (lds_t*)(Bs + (wave * 4 + j) * 512), 16, 0, 0);

#pragma unroll
    for (int it = 0; it < 8; ++it) {
        const int flat = it * 2048 + t * 8;
        const int row  = flat >> 8;              // 0..63
        const int koff = flat & 255;
        const float* src = feat + (size_t)min(bm + row, M - 1) * 256 + koff;
        const float4 a0 = *reinterpret_cast<const float4*>(src);
        const float4 a1 = *reinterpret_cast<const float4*>(src + 4);
        *reinterpret_cast<f16x4*>(&As[row * ASTRIDE + koff])     = cvt4h(a0);
        *reinterpret_cast<f16x4*>(&As[row * ASTRIDE + koff + 4]) = cvt4h(a1);
    }

    f32x4 acc[4][4];
#pragma unroll
    for (int mi = 0; mi < 4; ++mi)
#pragma unroll
        for (int ni = 0; ni < 4; ++ni)
            acc[mi][ni] = (f32x4){0.f, 0.f, 0.f, 0.f};

    for (int ki = 0; ki < 8; ++ki) {
        __syncthreads();                         // Bs(ki) + As ready

        f16x8 af[4], bfr[4];
#pragma unroll
        for (int mi = 0; mi < 4; ++mi)
            af[mi] = *reinterpret_cast<const f16x8*>(
                &As[(mi * 16 + l16) * ASTRIDE + ki * 32 + quad * 8]);
#pragma unroll
        for (int ni = 0; ni < 4; ++ni)
            bfr[ni] = *reinterpret_cast<const f16x8*>(
                &Bs[(wn + ni * 16 + l16) * 32 + quad * 8]);

        __syncthreads();                         // all waves done reading Bs
        if (ki < 7) {
            const int k0 = (ki + 1) * 32;
#pragma unroll
            for (int j = 0; j < 4; ++j)
                __builtin_amdgcn_global_load_lds((gm_t*)(Wp + bsrc[j] + k0),
                    (lds_t*)(Bs + (wave * 4 + j) * 512), 16, 0, 0);
        }
#pragma unroll
        for (int mi = 0; mi < 4; ++mi)
#pragma unroll
            for (int ni = 0; ni < 4; ++ni)
                acc[mi][ni] = __builtin_amdgcn_mfma_f32_16x16x32_f16(
                    af[mi], bfr[ni], acc[mi][ni], 0, 0, 0);
    }

    // C/D layout: col = lane&15, row = quad*4 + reg  [m89; dtype-independent m121/m124]
#pragma unroll
    for (int mi = 0; mi < 4; ++mi) {
#pragma unroll
        for (int r = 0; r < 4; ++r) {
            const int row = bm + mi * 16 + quad * 4 + r;
            if (row < M) {
#pragma unroll
                for (int ni = 0; ni < 4; ++ni) {
                    const int col = wn + ni * 16 + l16;
                    nf[(size_t)row * 256 + col] = (f16)(acc[mi][ni][r]);
                }
            }
        }
    }
}

// One wave per destination node; lane = feature f (F=64). 2 waves/block.
__global__ __launch_bounds__(128) void edge_aggregate(
    const int* __restrict__ rowptr,
    const int* __restrict__ colind,
    const float* __restrict__ pseudo,   // [E][2]
    const f16* __restrict__ nf,         // f16 [N][256] permuted [f*4+k]
    const float* __restrict__ mu,
    const float* __restrict__ inv_sigma,
    const float* __restrict__ bias,
    float* __restrict__ out,            // [N][64]
    int N)
{
    __shared__ f16 gbuf[2][64];         // per-wave: 16 edges x 4 kernels (f16)
    __shared__ int cbuf[2][16];
    const int wave = threadIdx.x >> 6;
    const int lane = threadIdx.x & 63;
    const int node = blockIdx.x * 2 + wave;
    if (node >= N) return;          // wave-uniform exit; no block barriers below

    const int kk = lane >> 4;
    const int ii = lane & 15;
    const float mx = mu[2 * kk], my = mu[2 * kk + 1];
    const float sa = inv_sigma[2 * kk], sb = inv_sigma[2 * kk + 1];
    const float sx = sa * sa, sy = sb * sb;

    const int e0 = rowptr[node];
    const int e1 = rowptr[node + 1];
    f16* gw = gbuf[wave];
    int* cw = cbuf[wave];

    float a4[4] = {0.f, 0.f, 0.f, 0.f};   // 4 independent chains
    for (int ec = e0; ec < e1; ec += 16) {
        const int cnt = min(16, e1 - ec);
        // stage all 16 slots: dead slots get g=0, col=0 (row-0 gather * 0)
        {
            const bool v = ii < cnt;
            const int e = v ? (ec + ii) : e0;
            const float2 p = *reinterpret_cast<const float2*>(pseudo + 2 * (size_t)e);
            const float dx = p.x - mx, dy = p.y - my;
            const float g = v ? __expf(-0.5f * (dx * dx * sx + dy * dy * sy)) : 0.f;
            gw[ii * 4 + kk] = (f16)g;
            if (kk == 0) cw[ii] = v ? colind[e] : 0;
        }
        __builtin_amdgcn_wave_barrier();
        __threadfence_block();      // drain LDS writes before broadcast reads
        const int cnt4 = (cnt + 3) & ~3;
        for (int i2 = 0; i2 < cnt4; i2 += 4) {
#pragma unroll
            for (int j = 0; j < 4; ++j) {
                const int c = cw[i2 + j];
                const f16x4 h = *reinterpret_cast<const f16x4*>(
                    nf + ((size_t)c << 8) + (lane << 2));
                const f16x2 g01 = *reinterpret_cast<const f16x2*>(&gw[(i2 + j) * 4]);
                const f16x2 g23 = *reinterpret_cast<const f16x2*>(&gw[(i2 + j) * 4 + 2]);
                const f16x2 h01 = __builtin_shufflevector(h, h, 0, 1);
                const f16x2 h23 = __builtin_shufflevector(h, h, 2, 3);
#if __has_builtin(__builtin_amdgcn_fdot2)
                a4[j] = __builtin_amdgcn_fdot2(h01, g01, a4[j], false);
                a4[j] = __builtin_amdgcn_fdot2(h23, g23, a4[j], false);
#else
                a4[j] += (float)h01.x * (float)g01.x + (float)h01.y * (float)g01.y
                       + (float)h23.x * (float)g23.x + (float)h23.y * (float)g23.y;
#endif
            }
        }
        __builtin_amdgcn_wave_barrier();
        __threadfence_block();      // reads done before next chunk's writes
    }
    out[((size_t)node << 6) + lane] =
        (a4[0] + a4[1]) + (a4[2] + a4[3]) + bias[lane];
}

extern "C" void kernel_launch(void* const* d_in, const int* in_sizes, int n_in,
                              void* d_out, int out_size, void* d_ws, size_t ws_size,
                              hipStream_t stream)
{
    const int*   rowptr    = (const int*)d_in[0];
    const int*   colind    = (const int*)d_in[1];
    // d_in[2] colptr, d_in[3] rowind, d_in[4] permute: inert in forward math
    const float* feat      = (const float*)d_in[5];
    const float* pseudo    = (const float*)d_in[6];
    const float* W_fc      = (const float*)d_in[7];
    const float* mu        = (const float*)d_in[8];
    const float* inv_sigma = (const float*)d_in[9];
    const float* bias      = (const float*)d_in[10];
    float* out = (float*)d_out;

    const int N = in_sizes[0] - 1;        // 50000
    f16* nf = (f16*)d_ws;                 // f16 [N][256] = 25.6 MB
    f16* Wp = (f16*)d_out;                // 128 KB overlay; edge rewrites
                                          // all of d_out afterwards

    hipLaunchKernelGGL(convert_W, dim3(64), dim3(256), 0, stream, W_fc, Wp);

    hipLaunchKernelGGL(gemm_fused, dim3((N + 63) / 64), dim3(256), 0, stream,
                       feat, Wp, nf, N);

    hipLaunchKernelGGL(edge_aggregate, dim3((N + 1) / 2), dim3(128), 0, stream,
                       rowptr, colind, pseudo, nf, mu, inv_sigma, bias, out, N);
}

// Round 9
// 182.647 us; speedup vs baseline: 1.0900x; 1.0382x over previous
//
#include <hip/hip_runtime.h>

// ---------------------------------------------------------------------------
// GMMConv forward — int8-gather edition:
//  0) convert_W: Wp[j'][k]=f16(W_fc[((j'&3)<<6)|(j'>>2)][k]) into a 128 KB
//     overlay at the start of d_out (edge rewrites all of d_out afterwards).
//  1) gemm_fused: f16 MFMA as R8 (A staged once per block fp32->f16 in LDS,
//     B-tiles DMA'd from L2-resident Wp). NEW epilogue: quantize acc to i8
//     with per-(row, 64-col-group) scale (shfl_xor absmax reduce), transpose
//     bytes through LDS (reusing Bs after its last read) -> one coalesced
//     16 KB store per block; scales (A/127^2) to sc[N][4].
//  2) edge_aggregate: one wave per dst node (CSR rowptr sorts edges by dst,
//     no atomics). Gaussians quantized to i8x4 in LDS; per edge: 1 dword nfq
//     (256 B/wave), 1 dword scale (16 B/wave), v_dot4_i32_i8 + cvt + fma.
//     Gather bytes/edge: 512 -> 272 (the R6/R8 data proved the kernel is
//     fabric-throughput-bound, so bytes are the only lever left).
//  Precision: i8 per-group quant err ~0.29/127 of group absmax; 64-term
//  random accumulation -> ~0.09 RMS, absmax ~0.6-1.0 vs threshold 2.19.
// ---------------------------------------------------------------------------

typedef _Float16 f16;
typedef __attribute__((ext_vector_type(4))) _Float16 f16x4;
typedef __attribute__((ext_vector_type(8))) _Float16 f16x8;
typedef __attribute__((ext_vector_type(4))) float f32x4;

__device__ inline f16x4 cvt4h(float4 v) {
    f16x4 h;
    h.x = (f16)v.x; h.y = (f16)v.y; h.z = (f16)v.z; h.w = (f16)v.w;
    return h;
}

__device__ inline int dot4_i8(int a, int b) {
#if __has_builtin(__builtin_amdgcn_sdot4)
    return __builtin_amdgcn_sdot4(a, b, 0, false);
#else
    return (int)(char)(a)       * (int)(char)(b)
         + (int)(char)(a >> 8)  * (int)(char)(b >> 8)
         + (int)(char)(a >> 16) * (int)(char)(b >> 16)
         + (int)(char)(a >> 24) * (int)(char)(b >> 24);
#endif
}

// W_fc fp32 [256][256] -> Wp f16 [256][256] with permuted rows.
__global__ __launch_bounds__(256) void convert_W(
    const float* __restrict__ W, f16* __restrict__ Wp)
{
    const int gid = blockIdx.x * 256 + threadIdx.x;   // 64 blocks -> 16384
    const int jp = gid >> 6, k4 = gid & 63;
    const int wrow = ((jp & 3) << 6) | (jp >> 2);
    reinterpret_cast<f16x4*>(Wp)[jp * 64 + k4] =
        cvt4h(reinterpret_cast<const float4*>(W)[wrow * 64 + k4]);
}

#define ASTRIDE 264                 // f16 per A-row in LDS (+8 pad)
#define AS_BYTES (64 * ASTRIDE * 2) // 33792, 16B aligned

// nfq[m][jp] = i8 quant of sum_k f16(feat[m][k]) * Wp[jp][k]
// sc[m][g]   = groupAbsmax / 127^2 for col group g = jp>>6
__global__ __launch_bounds__(256) void gemm_fused(
    const float* __restrict__ feat,   // fp32 [M][256]
    const f16* __restrict__ Wp,       // f16 [256][256] permuted rows
    char* __restrict__ nfq,           // i8 [M][256]
    float* __restrict__ sc,           // f32 [M][4]
    int M)
{
    __shared__ char smem[AS_BYTES + 256 * 32 * 2];  // As 33 KB + Bs/qt 16 KB
    f16* As = (f16*)smem;
    f16* Bs = (f16*)(smem + AS_BYTES);
    char* qt = smem + AS_BYTES;       // reuses Bs region in the epilogue
    const int t    = threadIdx.x;
    const int lane = t & 63;
    const int wave = t >> 6;
    const int bm   = blockIdx.x * 64;
    const int l16  = lane & 15;
    const int quad = lane >> 4;
    const int wn   = wave * 64;

    size_t bsrc[4];
#pragma unroll
    for (int j = 0; j < 4; ++j)
        bsrc[j] = (size_t)(wave * 64 + j * 16 + (lane >> 2)) * 256 + (lane & 3) * 8;

    typedef __attribute__((address_space(3))) void lds_t;
    typedef const __attribute__((address_space(1))) void gm_t;

    // kick off B DMA for k0=0, then stage A (fp32->f16) while it flies
#pragma unroll
    for (int j = 0; j < 4; ++j)
        __builtin_amdgcn_global_load_lds((gm_t*)(Wp + bsrc[j]),
            (lds_t*)(Bs + (wave * 4 + j) * 512), 16, 0, 0);

#pragma unroll
    for (int it = 0; it < 8; ++it) {
        const int flat = it * 2048 + t * 8;
        const int row  = flat >> 8;              // 0..63
        const int koff = flat & 255;
        const float* src = feat + (size_t)min(bm + row, M - 1) * 256 + koff;
        const float4 a0 = *reinterpret_cast<const float4*>(src);
        const float4 a1 = *reinterpret_cast<const float4*>(src + 4);
        *reinterpret_cast<f16x4*>(&As[row * ASTRIDE + koff])     = cvt4h(a0);
        *reinterpret_cast<f16x4*>(&As[row * ASTRIDE + koff + 4]) = cvt4h(a1);
    }

    f32x4 acc[4][4];
#pragma unroll
    for (int mi = 0; mi < 4; ++mi)
#pragma unroll
        for (int ni = 0; ni < 4; ++ni)
            acc[mi][ni] = (f32x4){0.f, 0.f, 0.f, 0.f};

    for (int ki = 0; ki < 8; ++ki) {
        __syncthreads();                         // Bs(ki) + As ready

        f16x8 af[4], bfr[4];
#pragma unroll
        for (int mi = 0; mi < 4; ++mi)
            af[mi] = *reinterpret_cast<const f16x8*>(
                &As[(mi * 16 + l16) * ASTRIDE + ki * 32 + quad * 8]);
#pragma unroll
        for (int ni = 0; ni < 4; ++ni)
            bfr[ni] = *reinterpret_cast<const f16x8*>(
                &Bs[(wn + ni * 16 + l16) * 32 + quad * 8]);

        __syncthreads();                         // all waves done reading Bs
        if (ki < 7) {
            const int k0 = (ki + 1) * 32;
#pragma unroll
            for (int j = 0; j < 4; ++j)
                __builtin_amdgcn_global_load_lds((gm_t*)(Wp + bsrc[j] + k0),
                    (lds_t*)(Bs + (wave * 4 + j) * 512), 16, 0, 0);
        }
#pragma unroll
        for (int mi = 0; mi < 4; ++mi)
#pragma unroll
            for (int ni = 0; ni < 4; ++ni)
                acc[mi][ni] = __builtin_amdgcn_mfma_f32_16x16x32_f16(
                    af[mi], bfr[ni], acc[mi][ni], 0, 0, 0);
    }
    // After the ki=7 second barrier: no more Bs reads anywhere -> qt can
    // safely overwrite the Bs region (MFMA/epilogue touch registers only).

    // quantize: per (row, this wave's 64 cols) absmax
    // C/D layout: col = lane&15, row = quad*4 + reg  [m89; dtype-independent]
#pragma unroll
    for (int mi = 0; mi < 4; ++mi) {
#pragma unroll
        for (int r = 0; r < 4; ++r) {
            float am = 0.f;
#pragma unroll
            for (int ni = 0; ni < 4; ++ni)
                am = fmaxf(am, fabsf(acc[mi][ni][r]));
            am = fmaxf(am, __shfl_xor(am, 1));   // reduce over l16 (same quad)
            am = fmaxf(am, __shfl_xor(am, 2));
            am = fmaxf(am, __shfl_xor(am, 4));
            am = fmaxf(am, __shfl_xor(am, 8));
            const float sinv = am > 0.f ? 127.f / am : 0.f;
            const int rl = mi * 16 + quad * 4 + r;
#pragma unroll
            for (int ni = 0; ni < 4; ++ni)
                qt[rl * 256 + wn + ni * 16 + l16] =
                    (char)(int)__builtin_rintf(acc[mi][ni][r] * sinv);
            if (l16 == 0) {
                const int row = bm + rl;
                if (row < M) sc[row * 4 + wave] = am * (1.f / 16129.f);
            }
        }
    }
    __syncthreads();

    // coalesced i8 store: thread t -> row t>>2, 64 B chunk (t&3)
    {
        const int rl  = t >> 2;
        const int co  = (t & 3) * 64;
        const int row = bm + rl;
        if (row < M) {
            const int4* s4 = reinterpret_cast<const int4*>(qt + rl * 256 + co);
            int4* d4 = reinterpret_cast<int4*>(nfq + (size_t)row * 256 + co);
#pragma unroll
            for (int j = 0; j < 4; ++j) d4[j] = s4[j];
        }
    }
}

// One wave per destination node; lane = feature f (F=64). 2 waves/block.
__global__ __launch_bounds__(128) void edge_aggregate(
    const int* __restrict__ rowptr,
    const int* __restrict__ colind,
    const float* __restrict__ pseudo,   // [E][2]
    const char* __restrict__ nfq,       // i8 [N][256] permuted [f*4+k]
    const float* __restrict__ sc,       // f32 [N][4] group scales
    const float* __restrict__ mu,
    const float* __restrict__ inv_sigma,
    const float* __restrict__ bias,
    float* __restrict__ out,            // [N][64]
    int N)
{
    __shared__ int gpack[2][16];        // per-wave: 16 edges, g quantized i8x4
    __shared__ int cbuf[2][16];
    const int wave = threadIdx.x >> 6;
    const int lane = threadIdx.x & 63;
    const int node = blockIdx.x * 2 + wave;
    if (node >= N) return;          // wave-uniform exit; no block barriers below

    const int kk = lane >> 4;
    const int ii = lane & 15;
    const float mx = mu[2 * kk], my = mu[2 * kk + 1];
    const float sa = inv_sigma[2 * kk], sb = inv_sigma[2 * kk + 1];
    const float sx = sa * sa, sy = sb * sb;

    const int e0 = rowptr[node];
    const int e1 = rowptr[node + 1];
    int* gp = gpack[wave];
    int* cw = cbuf[wave];

    float a4[4] = {0.f, 0.f, 0.f, 0.f};   // 4 independent chains
    for (int ec = e0; ec < e1; ec += 16) {
        const int cnt = min(16, e1 - ec);
        // stage all 16 slots: dead slots get g=0, col=0 (row-0 gather * 0)
        {
            const bool v = ii < cnt;
            const int e = v ? (ec + ii) : e0;
            const float2 p = *reinterpret_cast<const float2*>(pseudo + 2 * (size_t)e);
            const float dx = p.x - mx, dy = p.y - my;
            const float g = v ? __expf(-0.5f * (dx * dx * sx + dy * dy * sy)) : 0.f;
            ((char*)&gp[ii])[kk] = (char)(int)(g * 127.f + 0.5f);  // 0..127
            if (kk == 0) cw[ii] = v ? colind[e] : 0;
        }
        __builtin_amdgcn_wave_barrier();
        __threadfence_block();      // drain LDS writes before broadcast reads
        const int cnt4 = (cnt + 3) & ~3;
        for (int i2 = 0; i2 < cnt4; i2 += 4) {
#pragma unroll
            for (int j = 0; j < 4; ++j) {
                const int c = cw[i2 + j];
                const int q = *reinterpret_cast<const int*>(
                    nfq + ((size_t)c << 8) + (lane << 2));
                const float s = sc[c * 4 + (lane >> 4)];
                const int d = dot4_i8(q, gp[i2 + j]);
                a4[j] += s * (float)d;
            }
        }
        __builtin_amdgcn_wave_barrier();
        __threadfence_block();      // reads done before next chunk's writes
    }
    out[((size_t)node << 6) + lane] =
        (a4[0] + a4[1]) + (a4[2] + a4[3]) + bias[lane];
}

extern "C" void kernel_launch(void* const* d_in, const int* in_sizes, int n_in,
                              void* d_out, int out_size, void* d_ws, size_t ws_size,
                              hipStream_t stream)
{
    const int*   rowptr    = (const int*)d_in[0];
    const int*   colind    = (const int*)d_in[1];
    // d_in[2] colptr, d_in[3] rowind, d_in[4] permute: inert in forward math
    const float* feat      = (const float*)d_in[5];
    const float* pseudo    = (const float*)d_in[6];
    const float* W_fc      = (const float*)d_in[7];
    const float* mu        = (const float*)d_in[8];
    const float* inv_sigma = (const float*)d_in[9];
    const float* bias      = (const float*)d_in[10];
    float* out = (float*)d_out;

    const int N = in_sizes[0] - 1;        // 50000
    char*  nfq = (char*)d_ws;             // i8 [N][256] = 12.8 MB
    float* sc  = (float*)(nfq + (size_t)N * 256);  // f32 [N][4] = 0.8 MB
    f16*   Wp  = (f16*)d_out;             // 128 KB overlay; edge rewrites
                                          // all of d_out afterwards

    hipLaunchKernelGGL(convert_W, dim3(64), dim3(256), 0, stream, W_fc, Wp);

    hipLaunchKernelGGL(gemm_fused, dim3((N + 63) / 64), dim3(256), 0, stream,
                       feat, Wp, nfq, sc, N);

    hipLaunchKernelGGL(edge_aggregate, dim3((N + 1) / 2), dim3(128), 0, stream,
                       rowptr, colind, pseudo, nfq, sc, mu, inv_sigma, bias, out, N);
}